// Round 7
// baseline (41.791 us; speedup 1.0000x reference)
//
#include <hip/hip_runtime.h>
#include <hip/hip_bf16.h>

#define F_IN 128
#define F_OUT 64

typedef __attribute__((ext_vector_type(8))) short short8;
typedef __attribute__((ext_vector_type(4))) float f32x4;

__device__ __forceinline__ unsigned short f2bf_rne(float f) {
  unsigned int u = __builtin_bit_cast(unsigned int, f);
  u += 0x7fffu + ((u >> 16) & 1u);
  return (unsigned short)(u >> 16);
}
__device__ __forceinline__ float bfu2f(unsigned short u) {
  return __builtin_bit_cast(float, (unsigned int)u << 16);
}
__device__ __forceinline__ float bf_lo(unsigned int u) {
  return __builtin_bit_cast(float, u << 16);
}
__device__ __forceinline__ float bf_hi(unsigned int u) {
  return __builtin_bit_cast(float, u & 0xffff0000u);
}

// ---------------------------------------------------------------------------
// Kernel A (fused): blocks [0, gemm_blocks) compute pre = bf16(x @ W) via
// MFMA; blocks [gemm_blocks, ..) compute row_ptr by binary search.
// pre is stored as TWO PLANES of 32 features each (3.2 MB per plane) so the
// spmm's per-pass gather working set fits a 4 MiB XCD L2:
//   plane p, row r, col c' in [0,32)  <->  feature p*32 + c'.
// GEMM: wave -> 16-row m-tile; W^T staged bf16 in 16 KB LDS, XOR-swizzled;
// x single-rounded bf16 -> 1 MFMA per (ks, nt). Error budget OK (thr 3.32).
// ---------------------------------------------------------------------------
__global__ __launch_bounds__(256) void gcn_gemm_rowptr(
    const float* __restrict__ x, const float* __restrict__ w,
    unsigned short* __restrict__ pre,
    const int* __restrict__ edge_row, int* __restrict__ row_ptr,
    int n_nodes, int n_edges, int gemm_blocks) {
  const int tid = threadIdx.x;

  if (blockIdx.x >= gemm_blocks) {  // ---- rowptr path ----
    const int r = (blockIdx.x - gemm_blocks) * 256 + tid;
    if (r > n_nodes) return;
    int lo = 0, hi = n_edges;
    while (lo < hi) {
      const int mid = (lo + hi) >> 1;
      if (edge_row[mid] < r) lo = mid + 1; else hi = mid;
    }
    row_ptr[r] = lo;
    return;
  }

  // ---- GEMM path ----
  __shared__ __align__(16) unsigned short wt_hi[64 * 128];  // 16 KB

  {  // stage W^T: coalesced float4 reads, convert, scatter u16 into LDS
#pragma unroll
    for (int i = 0; i < 8; ++i) {
      const int flat4 = tid + i * 256;
      const float4 v = ((const float4*)w)[flat4];
      const float fv[4] = {v.x, v.y, v.z, v.w};
#pragma unroll
      for (int j = 0; j < 4; ++j) {
        const int flat = flat4 * 4 + j;          // flat = k*64 + n
        const int k = flat >> 6;
        const int n = flat & 63;
        int off = (n << 8) + (k << 1);
        off ^= (n & 7) << 4;
        *(unsigned short*)((char*)wt_hi + off) = f2bf_rne(fv[j]);
      }
    }
  }
  __syncthreads();

  const int lane = tid & 63;
  const int mt = blockIdx.x * 4 + (tid >> 6);
  const int m0 = mt * 16;
  if (m0 >= n_nodes) return;

  const int lrow = lane & 15;
  const int lk = lane >> 4;
  const bool full = (m0 + 16 <= n_nodes);
  const int arow = full ? (m0 + lrow) : min(m0 + lrow, n_nodes - 1);

  f32x4 acc[4];
#pragma unroll
  for (int i = 0; i < 4; ++i) acc[i] = (f32x4){0.f, 0.f, 0.f, 0.f};

#pragma unroll
  for (int ks = 0; ks < 4; ++ks) {
    const float4* xp =
        (const float4*)(x + (size_t)arow * F_IN + ks * 32 + lk * 8);
    const float4 q0 = xp[0];
    const float4 q1 = xp[1];
    const float fv[8] = {q0.x, q0.y, q0.z, q0.w, q1.x, q1.y, q1.z, q1.w};
    short8 ah;
#pragma unroll
    for (int i = 0; i < 8; ++i) ah[i] = (short)f2bf_rne(fv[i]);
#pragma unroll
    for (int nt = 0; nt < 4; ++nt) {
      const int n = nt * 16 + lrow;
      int off = (n << 8) + (ks * 64 + lk * 16);
      off ^= (n & 7) << 4;
      const short8 bh = *(const short8*)((const char*)wt_hi + off);
      acc[nt] = __builtin_amdgcn_mfma_f32_16x16x32_bf16(ah, bh, acc[nt], 0, 0, 0);
    }
  }

  // C/D: col = lane&15, row = (lane>>4)*4 + reg  [HW-verified]
  // Plane-split store: nt<2 -> plane 0, nt>=2 -> plane 1; col' = (nt&1)*16+lrow.
#pragma unroll
  for (int nt = 0; nt < 4; ++nt) {
    unsigned short* plane = pre + (size_t)(nt >> 1) * n_nodes * 32;
    const int coff = (nt & 1) * 16 + lrow;
#pragma unroll
    for (int r = 0; r < 4; ++r) {
      const int row = m0 + lk * 4 + r;
      if (full || row < n_nodes)
        plane[(size_t)row * 32 + coff] = f2bf_rne(acc[nt][r]);
    }
  }
}

// ---------------------------------------------------------------------------
// Kernel B: out[r][pass*32+f] = relu( sum_e val[e] * plane[col[e]][f] )
// gridDim.y = 2 passes; pass p gathers only plane p (3.2 MB -> L2-resident;
// x-fastest dispatch time-separates the passes). One wave per row; quarter
// q (16 lanes) handles edge 4g+q, lane loads uint = 2 bf16 of its feature
// pair. Per 32-edge batch: 16 bpermute broadcasts, then 8 INDEPENDENT
// gather instructions back-to-back, then 16 fmas. Padded slots: v=0,
// row-0 gather (L1-hot). 2 shfl_xor per feature at the end; quarter 0
// stores float2 (128 B per row per pass). Fixed order -> deterministic.
// ---------------------------------------------------------------------------
__global__ __launch_bounds__(256) void gcn_spmm(
    const unsigned short* __restrict__ pre, const int* __restrict__ row_ptr,
    const int* __restrict__ edge_col, const float* __restrict__ edge_val,
    float* __restrict__ out, int n_nodes) {
  const int lane = threadIdx.x & 63;
  const int q  = lane >> 4;   // quarter = edge slot within group of 4
  const int fl = lane & 15;   // feature-pair index within the 32-col plane
  const int pass = blockIdx.y;
  const unsigned short* plane = pre + (size_t)pass * n_nodes * 32;

  int row = (int)((blockIdx.x * blockDim.x + threadIdx.x) >> 6);
  row = __builtin_amdgcn_readfirstlane(row);
  if (row >= n_nodes) return;
  const int e0 = row_ptr[row];
  const int e1 = row_ptr[row + 1];

  float a0 = 0.f, a1 = 0.f;
  const char* prebase = (const char*)plane + ((size_t)fl << 2);  // fl-th uint

  for (int base = e0; base < e1; base += 64) {
    const int cnt = min(64, e1 - base);
    int myc = 0;
    float myv = 0.f;
    if (lane < cnt) {
      myc = edge_col[base + lane] << 6;  // byte offset of plane row (32*2B)
      myv = edge_val[base + lane];
    }
    const int nb = (cnt + 31) >> 5;  // 32 edges per iteration
    for (int b = 0; b < nb; ++b) {
      const int j0 = b * 32;
      int   cc[8];
      float vv[8];
#pragma unroll
      for (int g = 0; g < 8; ++g) {
        const int idx = j0 + g * 4 + q;
        cc[g] = __shfl(myc, idx);
        vv[g] = __shfl(myv, idx);
      }
      unsigned int p[8];
#pragma unroll
      for (int g = 0; g < 8; ++g)
        p[g] = *(const unsigned int*)(prebase + (size_t)(unsigned int)cc[g]);
#pragma unroll
      for (int g = 0; g < 8; ++g) {
        a0 = fmaf(vv[g], bf_lo(p[g]), a0);
        a1 = fmaf(vv[g], bf_hi(p[g]), a1);
      }
    }
  }

  // reduce across quarters (lanes differ only in q)
  a0 += __shfl_xor(a0, 16); a0 += __shfl_xor(a0, 32);
  a1 += __shfl_xor(a1, 16); a1 += __shfl_xor(a1, 32);

  if (q == 0) {
    float2 o = make_float2(fmaxf(a0, 0.f), fmaxf(a1, 0.f));
    *(float2*)(out + (size_t)row * F_OUT + pass * 32 + fl * 2) = o;
  }
}

extern "C" void kernel_launch(void* const* d_in, const int* in_sizes, int n_in,
                              void* d_out, int out_size, void* d_ws, size_t ws_size,
                              hipStream_t stream) {
  const float* x        = (const float*)d_in[0];
  const float* w        = (const float*)d_in[1];
  const int*   edge_row = (const int*)d_in[2];
  const int*   edge_col = (const int*)d_in[3];
  const float* edge_val = (const float*)d_in[4];
  float* out = (float*)d_out;

  const int n_nodes = in_sizes[0] / F_IN;   // 50000
  const int n_edges = in_sizes[2];          // 800000

  unsigned short* pre = (unsigned short*)d_ws;  // 2 planes x n_nodes*32 bf16
  int* row_ptr = (int*)((char*)d_ws +
                        (size_t)n_nodes * F_OUT * sizeof(unsigned short));

  const int m_tiles = (n_nodes + 15) / 16;
  const int gemm_blocks = (m_tiles + 3) / 4;
  const int rp_blocks = (n_nodes + 1 + 255) / 256;
  gcn_gemm_rowptr<<<gemm_blocks + rp_blocks, 256, 0, stream>>>(
      x, w, pre, edge_row, row_ptr, n_nodes, n_edges, gemm_blocks);

  const int spmm_blocks = ((size_t)n_nodes * 64 + 255) / 256;
  gcn_spmm<<<dim3(spmm_blocks, 2), 256, 0, stream>>>(
      pre, row_ptr, edge_col, edge_val, out, n_nodes);
}

// Round 8
// 33.480 us; speedup vs baseline: 1.2482x; 1.2482x over previous
//
#include <hip/hip_runtime.h>
#include <hip/hip_bf16.h>

#define F_IN 128
#define F_OUT 64

typedef __attribute__((ext_vector_type(8))) short short8;
typedef __attribute__((ext_vector_type(4))) float f32x4;

__device__ __forceinline__ unsigned short f2bf_rne(float f) {
  unsigned int u = __builtin_bit_cast(unsigned int, f);
  u += 0x7fffu + ((u >> 16) & 1u);
  return (unsigned short)(u >> 16);
}
__device__ __forceinline__ float bf_lo(unsigned int u) {
  return __builtin_bit_cast(float, u << 16);
}
__device__ __forceinline__ float bf_hi(unsigned int u) {
  return __builtin_bit_cast(float, u & 0xffff0000u);
}

// ---------------------------------------------------------------------------
// Kernel A (fused): blocks [0, gemm_blocks) compute pre = bf16(x @ W) via
// MFMA; blocks [gemm_blocks, ..) compute row_ptr by binary search.
// GEMM: wave -> 16-row m-tile; W^T staged bf16 in 16 KB LDS, XOR-swizzled;
// x single-rounded bf16 -> 1 MFMA per (ks, nt). Error budget OK (thr 3.32).
// ---------------------------------------------------------------------------
__global__ __launch_bounds__(256) void gcn_gemm_rowptr(
    const float* __restrict__ x, const float* __restrict__ w,
    unsigned short* __restrict__ pre,
    const int* __restrict__ edge_row, int* __restrict__ row_ptr,
    int n_nodes, int n_edges, int gemm_blocks) {
  const int tid = threadIdx.x;

  if (blockIdx.x >= gemm_blocks) {  // ---- rowptr path ----
    const int r = (blockIdx.x - gemm_blocks) * 256 + tid;
    if (r > n_nodes) return;
    int lo = 0, hi = n_edges;
    while (lo < hi) {
      const int mid = (lo + hi) >> 1;
      if (edge_row[mid] < r) lo = mid + 1; else hi = mid;
    }
    row_ptr[r] = lo;
    return;
  }

  // ---- GEMM path ----
  __shared__ __align__(16) unsigned short wt_hi[64 * 128];  // 16 KB

  {  // stage W^T: coalesced float4 reads, convert, scatter u16 into LDS
#pragma unroll
    for (int i = 0; i < 8; ++i) {
      const int flat4 = tid + i * 256;
      const float4 v = ((const float4*)w)[flat4];
      const float fv[4] = {v.x, v.y, v.z, v.w};
#pragma unroll
      for (int j = 0; j < 4; ++j) {
        const int flat = flat4 * 4 + j;          // flat = k*64 + n
        const int k = flat >> 6;
        const int n = flat & 63;
        int off = (n << 8) + (k << 1);
        off ^= (n & 7) << 4;
        *(unsigned short*)((char*)wt_hi + off) = f2bf_rne(fv[j]);
      }
    }
  }
  __syncthreads();

  const int lane = tid & 63;
  const int mt = blockIdx.x * 4 + (tid >> 6);
  const int m0 = mt * 16;
  if (m0 >= n_nodes) return;

  const int lrow = lane & 15;
  const int lk = lane >> 4;
  const bool full = (m0 + 16 <= n_nodes);
  const int arow = full ? (m0 + lrow) : min(m0 + lrow, n_nodes - 1);

  f32x4 acc[4];
#pragma unroll
  for (int i = 0; i < 4; ++i) acc[i] = (f32x4){0.f, 0.f, 0.f, 0.f};

#pragma unroll
  for (int ks = 0; ks < 4; ++ks) {
    const float4* xp =
        (const float4*)(x + (size_t)arow * F_IN + ks * 32 + lk * 8);
    const float4 q0 = xp[0];
    const float4 q1 = xp[1];
    const float fv[8] = {q0.x, q0.y, q0.z, q0.w, q1.x, q1.y, q1.z, q1.w};
    short8 ah;
#pragma unroll
    for (int i = 0; i < 8; ++i) ah[i] = (short)f2bf_rne(fv[i]);
#pragma unroll
    for (int nt = 0; nt < 4; ++nt) {
      const int n = nt * 16 + lrow;
      int off = (n << 8) + (ks * 64 + lk * 16);
      off ^= (n & 7) << 4;
      const short8 bh = *(const short8*)((const char*)wt_hi + off);
      acc[nt] = __builtin_amdgcn_mfma_f32_16x16x32_bf16(ah, bh, acc[nt], 0, 0, 0);
    }
  }

  // C/D: col = lane&15, row = (lane>>4)*4 + reg  [HW-verified]
#pragma unroll
  for (int nt = 0; nt < 4; ++nt) {
#pragma unroll
    for (int r = 0; r < 4; ++r) {
      const int row = m0 + lk * 4 + r;
      if (full || row < n_nodes)
        pre[(size_t)row * F_OUT + nt * 16 + lrow] = f2bf_rne(acc[nt][r]);
    }
  }
}

// ---------------------------------------------------------------------------
// Kernel B: out[r][f] = relu( sum_e val[e] * pre_bf16[col[e]][f] )
// FOUR ROWS PER WAVE; quarter q (16 lanes) OWNS row base+q exclusively:
// lane (q,fl) accumulates features [fl*4, fl*4+4) of its row (uint2 gather
// = 4 bf16). Per 16-step batch: one coalesced metadata preload per quarter
// (lane fl holds edge e0q+sb+fl), 32 bpermute broadcasts, then 16
// INDEPENDENT gather instructions back-to-back (each serving 4 edges),
// then 64 fmas. Steps run to max degree of the 4 rows; padded slots gather
// row 0 (L1-hot) with v=0. No cross-lane reduce; the wave's store is one
// contiguous 1 KB write (4 rows x 256 B). Fixed order -> deterministic.
// ---------------------------------------------------------------------------
__global__ __launch_bounds__(256) void gcn_spmm(
    const unsigned short* __restrict__ pre, const int* __restrict__ row_ptr,
    const int* __restrict__ edge_col, const float* __restrict__ edge_val,
    float* __restrict__ out, int n_nodes) {
  const int lane = threadIdx.x & 63;
  const int q  = lane >> 4;   // quarter -> owns row rbase+q
  const int fl = lane & 15;   // feature quad within the row
  const int wid = (int)((blockIdx.x * blockDim.x + threadIdx.x) >> 6);
  const int rbase = wid * 4;
  if (rbase >= n_nodes) return;

  const int myrow = rbase + q;
  const bool valid = myrow < n_nodes;
  const int rowc = valid ? myrow : n_nodes - 1;
  const int e0 = row_ptr[rowc];
  const int e1 = valid ? row_ptr[rowc + 1] : e0;

  // max degree across the 4 quarters (bits 4,5 of lane = quarter id)
  int md = e1 - e0;
  md = max(md, __shfl_xor(md, 16));
  md = max(md, __shfl_xor(md, 32));

  float a0 = 0.f, a1 = 0.f, a2 = 0.f, a3 = 0.f;
  const char* prebase = (const char*)pre + ((size_t)fl << 3);  // fl-th uint2

  for (int sb = 0; sb < md; sb += 16) {
    // preload: lane (q,fl) holds metadata of edge e0q + sb + fl
    int myc = 0;
    float myv = 0.f;
    const int ei = e0 + sb + fl;
    if (ei < e1) {
      myc = edge_col[ei] << 7;  // byte offset of pre row (64 * 2B)
      myv = edge_val[ei];
    }
    const int qb = lane & 48;  // q*16
    int   cc[16];
    float vv[16];
#pragma unroll
    for (int j = 0; j < 16; ++j) {
      cc[j] = __shfl(myc, qb + j);
      vv[j] = __shfl(myv, qb + j);
    }
    uint2 p[16];
#pragma unroll
    for (int j = 0; j < 16; ++j)
      p[j] = *(const uint2*)(prebase + (size_t)(unsigned int)cc[j]);
#pragma unroll
    for (int j = 0; j < 16; ++j) {
      a0 = fmaf(vv[j], bf_lo(p[j].x), a0);
      a1 = fmaf(vv[j], bf_hi(p[j].x), a1);
      a2 = fmaf(vv[j], bf_lo(p[j].y), a2);
      a3 = fmaf(vv[j], bf_hi(p[j].y), a3);
    }
  }

  if (valid) {
    float4 o;
    o.x = fmaxf(a0, 0.f);
    o.y = fmaxf(a1, 0.f);
    o.z = fmaxf(a2, 0.f);
    o.w = fmaxf(a3, 0.f);
    *(float4*)(out + (size_t)myrow * F_OUT + fl * 4) = o;  // wave: 1 KB contig
  }
}

extern "C" void kernel_launch(void* const* d_in, const int* in_sizes, int n_in,
                              void* d_out, int out_size, void* d_ws, size_t ws_size,
                              hipStream_t stream) {
  const float* x        = (const float*)d_in[0];
  const float* w        = (const float*)d_in[1];
  const int*   edge_row = (const int*)d_in[2];
  const int*   edge_col = (const int*)d_in[3];
  const float* edge_val = (const float*)d_in[4];
  float* out = (float*)d_out;

  const int n_nodes = in_sizes[0] / F_IN;   // 50000
  const int n_edges = in_sizes[2];          // 800000

  unsigned short* pre = (unsigned short*)d_ws;  // n_nodes*64 bf16 = 6.4 MB
  int* row_ptr = (int*)((char*)d_ws +
                        (size_t)n_nodes * F_OUT * sizeof(unsigned short));

  const int m_tiles = (n_nodes + 15) / 16;
  const int gemm_blocks = (m_tiles + 3) / 4;
  const int rp_blocks = (n_nodes + 1 + 255) / 256;
  gcn_gemm_rowptr<<<gemm_blocks + rp_blocks, 256, 0, stream>>>(
      x, w, pre, edge_row, row_ptr, n_nodes, n_edges, gemm_blocks);

  // 4 rows per wave, 4 waves per block -> 16 rows per block
  const int spmm_blocks = (n_nodes + 15) / 16;
  gcn_spmm<<<spmm_blocks, 256, 0, stream>>>(pre, row_ptr, edge_col, edge_val,
                                            out, n_nodes);
}